// Round 7
// baseline (8915.432 us; speedup 1.0000x reference)
//
#include <hip/hip_runtime.h>
#include <hip/hip_bf16.h>

#define SEQ  512
#define HID  1024
#define G4   4096
#define NBLK 128   // blocks per layer; grid = 256

typedef short bf16x8 __attribute__((ext_vector_type(8)));
typedef float f32x4  __attribute__((ext_vector_type(4)));
typedef unsigned long long u64;

static __device__ __forceinline__ unsigned short f2b(float f) {
  union { float f; unsigned u; } v; v.f = f;
  unsigned r = (v.u + 0x7FFFu + ((v.u >> 16) & 1u)) >> 16;  // RNE
  return (unsigned short)r;
}
static __device__ __forceinline__ float b2f_lo(unsigned u) {
  union { unsigned u; float f; } v; v.u = u << 16; return v.f;
}
static __device__ __forceinline__ float b2f_hi(unsigned u) {
  union { unsigned u; float f; } v; v.u = u & 0xFFFF0000u; return v.f;
}

// x (B,S,I) f32 -> xb row-major (S*B, I) bf16, row r = s*64+b
__global__ __launch_bounds__(256) void k_castx(const float* __restrict__ x,
                                               unsigned short* __restrict__ xb) {
  int idx = blockIdx.x * 256 + threadIdx.x;
  int r = idx >> 8, kq = idx & 255;
  int b = r & 63, s = r >> 6;
  float4 v = *reinterpret_cast<const float4*>(x + ((size_t)b * SEQ + s) * HID + (size_t)kq * 4);
  ushort4 o;
  o.x = f2b(v.x); o.y = f2b(v.y); o.z = f2b(v.z); o.w = f2b(v.w);
  *reinterpret_cast<ushort4*>(xb + (size_t)r * HID + kq * 4) = o;
}

// W (K=1024, N=4096) f32 -> WT (N=4096, K=1024) bf16
__global__ __launch_bounds__(256) void k_wtrans(const float* __restrict__ W,
                                                unsigned short* __restrict__ WT) {
  __shared__ float tls[32][33];
  int tile = blockIdx.x;
  int nt = tile & 127, kt = tile >> 7;
  int tx = threadIdx.x & 31, ty = threadIdx.x >> 5;
  int k0 = kt * 32, n0 = nt * 32;
  for (int i = 0; i < 4; ++i)
    tls[ty + 8 * i][tx] = W[(size_t)(k0 + ty + 8 * i) * G4 + n0 + tx];
  __syncthreads();
  for (int i = 0; i < 4; ++i)
    WT[(size_t)(n0 + ty + 8 * i) * HID + k0 + tx] = f2b(tls[tx][ty + 8 * i]);
}

// Poll 128 per-block flag words (128B apart, single-writer each, no RMW).
static __device__ __forceinline__ void poll_flags128(unsigned* flags, unsigned tgt) {
  const int l = threadIdx.x & 63;
  unsigned* p0 = flags + l * 32;
  unsigned* p1 = flags + (64 + l) * 32;
  long sp = 0;
  for (;;) {
    unsigned v0 = __hip_atomic_load(p0, __ATOMIC_RELAXED, __HIP_MEMORY_SCOPE_AGENT);
    unsigned v1 = __hip_atomic_load(p1, __ATOMIC_RELAXED, __HIP_MEMORY_SCOPE_AGENT);
    if (__all((v0 >= tgt) && (v1 >= tgt))) break;
    if (++sp > 2000000L) break;   // bailout: wrong answer beats a hang
    __builtin_amdgcn_s_sleep(1);
  }
  asm volatile("" ::: "memory");
}

static __device__ __forceinline__ void lds_wait(int* f, int tgt) {
  long sp = 0;
  while (__hip_atomic_load(f, __ATOMIC_RELAXED, __HIP_MEMORY_SCOPE_WORKGROUP) < tgt) {
    if (++sp > 50000000L) break;
    __builtin_amdgcn_s_sleep(1);
  }
  asm volatile("" ::: "memory");
}

// Both LSTM layers, one persistent launch. Blocks 0-127 layer0, 128-255 layer1.
// Wave tiling (B-frag reuse): each wave owns 2 row-tiles (32 batch rows) x
// 1 col-tile (16 gate cols) -> one ds_read_b128 B-frag feeds 2 MFMAs, halving
// LDS traffic vs 1x2 tiling. Weight LDS rows are gate-interleaved
// (c = hc*4+gate) so one col-tile holds all 4 gates; epilogue gathers i/f/g/o
// via shfl_xor(1,2) in 4-lane groups, pairs h-cols via shfl_xor(4), one u32
// store per even-hc lane. Sync = r5 scheme (best measured): per-block flag
// words, single poller wave + LDS relay.
__global__ __launch_bounds__(512, 1) void k_scan2(
    const unsigned short* __restrict__ xb,
    const unsigned short* __restrict__ WxT0, const unsigned short* __restrict__ WhT0,
    const float* __restrict__ b0,
    const unsigned short* __restrict__ WxT1, const unsigned short* __restrict__ WhT1,
    const float* __restrict__ b1,
    unsigned short* __restrict__ h1,
    unsigned short* __restrict__ h2, int h2mod,
    float* __restrict__ out,
    unsigned* __restrict__ bars) {
  __shared__ unsigned short wlds[32 * 2048];   // 128 KB weights [c][k], swizzled
  __shared__ float x_lds[2][4][8][64];         // x-partials in raw MFMA layout
  __shared__ unsigned lds_arr;
  __shared__ int hrdy, xrdy;

  const int bk  = blockIdx.x;
  const int layer = bk >> 7;
  const int nb  = bk & 127;
  const int tid = threadIdx.x;
  const int w   = tid >> 6;
  const int l   = tid & 63;
  const int lq  = l >> 4, lr = l & 15;
  const int rt2 = (w >> 1) & 1;      // row-group: rows rt2*32 .. +31
  const int ct  = w & 1;             // col-tile: LDS weight rows ct*16 .. +15
  const bool is_h = (w >= 4);

  const unsigned short* WxT = layer ? WxT1 : WxT0;
  const unsigned short* WhT = layer ? WhT1 : WhT0;
  const float* bias = layer ? b1 : b0;
  const unsigned short* aseq = layer ? h1 : xb;
  unsigned short* hout = layer ? h2 : h1;
  const int hmod = layer ? h2mod : 512;
  float* fout = layer ? out : nullptr;
  unsigned* ownflags = bars + layer * 4096;    // my layer's 128 flag words
  unsigned* l0flags  = bars;                   // layer0 flags
  unsigned* myflag   = ownflags + nb * 32;     // this block's word (128B apart)

  if (tid == 0) { lds_arr = 0; hrdy = 0; xrdy = 0; }

  // ---- one-time: stage weight slice into LDS, gate-interleaved rows ----
  // LDS row c (0..31) = hc_local*4 + gate; gcol = gate*1024 + nb*8 + hc_local
  {
    int c = tid >> 4, seg = tid & 15;
    int gate = c & 3, hcl = c >> 2;
    int gcol = gate * 1024 + nb * 8 + hcl;
    const unsigned short* sx = WxT + (size_t)gcol * HID;
    const unsigned short* sh = WhT + (size_t)gcol * HID;
    for (int j = 0; j < 16; ++j) {
      int kk = seg * 128 + j * 8;
      const unsigned short* src = (kk < 1024) ? (sx + kk) : (sh + kk - 1024);
      uint4 v = *reinterpret_cast<const uint4*>(src);
      int db = (c * 4096 + kk * 2) ^ ((c & 7) << 4);
      *reinterpret_cast<uint4*>(reinterpret_cast<char*>(wlds) + db) = v;
    }
  }

  char* wbase = reinterpret_cast<char*>(wlds);
  const int c_w = ct * 16 + lr;                 // my weight LDS row
  const int csw = (c_w & 7) << 4;
  const int cb  = c_w * 4096 + lq * 16;
  const int gate = lr & 3;
  const int hcl  = ct * 4 + (lr >> 2);          // block-local h-col 0..7
  const float bias_c = bias[gate * 1024 + nb * 8 + hcl];

  float cst[8] = {0.f};   // c-state: 2 row-groups x 4 rows, 1 h-col per lane

  __syncthreads();
  if (is_h) __builtin_amdgcn_s_setprio(1);

  // ---- prologue: x-projection for step 0 into x_lds[0] ----
  if (!is_h) {
    if (layer) poll_flags128(l0flags, 1u);       // h1[0] complete
    const bf16x8* ax0 = reinterpret_cast<const bf16x8*>(aseq)
                        + (size_t)(rt2 * 32 + lr) * 128 + lq;
    const bf16x8* ax1 = ax0 + 16 * 128;
    f32x4 acc[2][4] = {};
#pragma unroll 8
    for (int ks = 0; ks < 32; ++ks) {
      bf16x8 a0 = ax0[ks * 4];
      bf16x8 a1 = ax1[ks * 4];
      bf16x8 bb = *reinterpret_cast<const bf16x8*>(wbase + ((cb + ks * 64) ^ csw));
      acc[0][ks & 3] = __builtin_amdgcn_mfma_f32_16x16x32_bf16(a0, bb, acc[0][ks & 3], 0, 0, 0);
      acc[1][ks & 3] = __builtin_amdgcn_mfma_f32_16x16x32_bf16(a1, bb, acc[1][ks & 3], 0, 0, 0);
    }
#pragma unroll
    for (int ar = 0; ar < 2; ++ar) {
      f32x4 s = (acc[ar][0] + acc[ar][1]) + (acc[ar][2] + acc[ar][3]);
      x_lds[0][w][ar * 4 + 0][l] = s.x + bias_c;
      x_lds[0][w][ar * 4 + 1][l] = s.y + bias_c;
      x_lds[0][w][ar * 4 + 2][l] = s.z + bias_c;
      x_lds[0][w][ar * 4 + 3][l] = s.w + bias_c;
    }
  }
  __syncthreads();

  for (int t = 0; t < SEQ; ++t) {
    if (!is_h) {
      // ---------- L1 x-waves: copy h2[t-1] -> fout FIRST (drain hides under MFMA) ----------
      if (fout && t > 0) {
        int tc = t - 1;
        const unsigned* sp32 = reinterpret_cast<const unsigned*>(
            hout + (size_t)(tc % hmod) * (64 * HID)) + (size_t)l * 512 + nb * 4 + (w & 3);
        unsigned pv = (hmod == 4)
            ? __hip_atomic_load(sp32, __ATOMIC_RELAXED, __HIP_MEMORY_SCOPE_AGENT)
            : *sp32;
        *reinterpret_cast<float2*>(fout + (size_t)l * (SEQ * HID) + (size_t)tc * HID
                                   + nb * 8 + (w & 3) * 2) = make_float2(b2f_lo(pv), b2f_hi(pv));
      }
      // ---------- x-waves: project input of step t+1 into x_lds[(t+1)&1] ----------
      if (t + 1 < SEQ) {
        if (layer) {
          if (w == 0) {
            poll_flags128(l0flags, (unsigned)(t + 2));   // h1[t+1] complete
            __hip_atomic_store(&xrdy, t + 1, __ATOMIC_RELAXED, __HIP_MEMORY_SCOPE_WORKGROUP);
          } else {
            lds_wait(&xrdy, t + 1);
          }
        }
        const bf16x8* ax0 = reinterpret_cast<const bf16x8*>(aseq)
                            + ((size_t)(t + 1) * 64 + rt2 * 32 + lr) * 128 + lq;
        const bf16x8* ax1 = ax0 + 16 * 128;
        f32x4 acc[2][4] = {};
#pragma unroll 8
        for (int ks = 0; ks < 32; ++ks) {
          bf16x8 a0 = ax0[ks * 4];
          bf16x8 a1 = ax1[ks * 4];
          bf16x8 bb = *reinterpret_cast<const bf16x8*>(wbase + ((cb + ks * 64) ^ csw));
          acc[0][ks & 3] = __builtin_amdgcn_mfma_f32_16x16x32_bf16(a0, bb, acc[0][ks & 3], 0, 0, 0);
          acc[1][ks & 3] = __builtin_amdgcn_mfma_f32_16x16x32_bf16(a1, bb, acc[1][ks & 3], 0, 0, 0);
        }
        int bn2 = (t + 1) & 1;
#pragma unroll
        for (int ar = 0; ar < 2; ++ar) {
          f32x4 s = (acc[ar][0] + acc[ar][1]) + (acc[ar][2] + acc[ar][3]);
          x_lds[bn2][w][ar * 4 + 0][l] = s.x + bias_c;
          x_lds[bn2][w][ar * 4 + 1][l] = s.y + bias_c;
          x_lds[bn2][w][ar * 4 + 2][l] = s.z + bias_c;
          x_lds[bn2][w][ar * 4 + 3][l] = s.w + bias_c;
        }
      }
    } else {
      // ---------- h-waves: recurrence critical path ----------
      const int bn = t & 1;
      const int hw = w - 4;
      f32x4 acc[2][4];
#pragma unroll
      for (int ar = 0; ar < 2; ++ar) {
        acc[ar][0] = f32x4{x_lds[bn][hw][ar * 4 + 0][l], x_lds[bn][hw][ar * 4 + 1][l],
                           x_lds[bn][hw][ar * 4 + 2][l], x_lds[bn][hw][ar * 4 + 3][l]};
        acc[ar][1] = f32x4{0.f, 0.f, 0.f, 0.f};
        acc[ar][2] = f32x4{0.f, 0.f, 0.f, 0.f};
        acc[ar][3] = f32x4{0.f, 0.f, 0.f, 0.f};
      }

      if (t > 0) {
        if (w == 4) {
          poll_flags128(ownflags, (unsigned)t);          // all blocks finished t-1
          __hip_atomic_store(&hrdy, t, __ATOMIC_RELAXED, __HIP_MEMORY_SCOPE_WORKGROUP);
        } else {
          lds_wait(&hrdy, t);
        }
        const size_t hbase = (size_t)((t - 1) % hmod) * (64 * HID);
        if (hmod != 4) {
          const bf16x8* hp0 = reinterpret_cast<const bf16x8*>(hout + hbase)
                              + (size_t)(rt2 * 32 + lr) * 128 + lq;
          const bf16x8* hp1 = hp0 + 16 * 128;
#pragma unroll 8
          for (int ks = 0; ks < 32; ++ks) {
            bf16x8 a0 = hp0[ks * 4];
            bf16x8 a1 = hp1[ks * 4];
            bf16x8 bb = *reinterpret_cast<const bf16x8*>(wbase + ((cb + 2048 + ks * 64) ^ csw));
            acc[0][ks & 3] = __builtin_amdgcn_mfma_f32_16x16x32_bf16(a0, bb, acc[0][ks & 3], 0, 0, 0);
            acc[1][ks & 3] = __builtin_amdgcn_mfma_f32_16x16x32_bf16(a1, bb, acc[1][ks & 3], 0, 0, 0);
          }
        } else {
          const u64* hq0 = reinterpret_cast<const u64*>(hout + hbase)
                           + (size_t)(rt2 * 32 + lr) * 256 + lq * 2;
          const u64* hq1 = hq0 + 16 * 256;
#pragma unroll 8
          for (int ks = 0; ks < 32; ++ks) {
            u64 q0 = __hip_atomic_load(hq0 + ks * 8,     __ATOMIC_RELAXED, __HIP_MEMORY_SCOPE_AGENT);
            u64 q1 = __hip_atomic_load(hq0 + ks * 8 + 1, __ATOMIC_RELAXED, __HIP_MEMORY_SCOPE_AGENT);
            u64 q2 = __hip_atomic_load(hq1 + ks * 8,     __ATOMIC_RELAXED, __HIP_MEMORY_SCOPE_AGENT);
            u64 q3 = __hip_atomic_load(hq1 + ks * 8 + 1, __ATOMIC_RELAXED, __HIP_MEMORY_SCOPE_AGENT);
            union { u64 q[2]; bf16x8 v; } u0; u0.q[0] = q0; u0.q[1] = q1;
            union { u64 q[2]; bf16x8 v; } u1; u1.q[0] = q2; u1.q[1] = q3;
            bf16x8 bb = *reinterpret_cast<const bf16x8*>(wbase + ((cb + 2048 + ks * 64) ^ csw));
            acc[0][ks & 3] = __builtin_amdgcn_mfma_f32_16x16x32_bf16(u0.v, bb, acc[0][ks & 3], 0, 0, 0);
            acc[1][ks & 3] = __builtin_amdgcn_mfma_f32_16x16x32_bf16(u1.v, bb, acc[1][ks & 3], 0, 0, 0);
          }
        }
      }

      // ---- in-register epilogue: gather i/f/g/o across 4-lane gate groups ----
      float hvf[2][4], hn4[2][4];
#pragma unroll
      for (int ar = 0; ar < 2; ++ar) {
        f32x4 s = (acc[ar][0] + acc[ar][1]) + (acc[ar][2] + acc[ar][3]);
        float sv[4] = {s.x, s.y, s.z, s.w};
#pragma unroll
        for (int r = 0; r < 4; ++r) {
          float a  = sv[r];
          float b  = __shfl_xor(a, 1, 64);
          float c2 = __shfl_xor(a, 2, 64);
          float d2 = __shfl_xor(b, 2, 64);
          float u0g = (gate & 1) ? b : a;
          float u1g = (gate & 1) ? a : b;
          float u2g = (gate & 1) ? d2 : c2;
          float u3g = (gate & 1) ? c2 : d2;
          float gi = (gate & 2) ? u2g : u0g;
          float gf = (gate & 2) ? u3g : u1g;
          float gg = (gate & 2) ? u0g : u2g;
          float go = (gate & 2) ? u1g : u3g;
          float ig = 1.f / (1.f + __expf(-gi));
          float fg = 1.f / (1.f + __expf(-gf));
          float e2 = __expf(2.f * gg);
          float gv = (e2 - 1.f) / (e2 + 1.f);
          float og = 1.f / (1.f + __expf(-go));
          float& cr = cst[ar * 4 + r];
          cr = fg * cr + ig * gv;
          float e2c = __expf(2.f * cr);
          hvf[ar][r] = og * (e2c - 1.f) / (e2c + 1.f);
        }
      }
      // pair adjacent h-cols (lane^4) and store one u32 per even-hc lane
#pragma unroll
      for (int ar = 0; ar < 2; ++ar)
#pragma unroll
        for (int r = 0; r < 4; ++r)
          hn4[ar][r] = __shfl_xor(hvf[ar][r], 4, 64);

      unsigned* hw32 = reinterpret_cast<unsigned*>(hout + (size_t)(t % hmod) * (64 * HID));
      if ((lr & 4) == 0) {
        const int ucol = nb * 4 + ct * 2 + (lr >> 3);
#pragma unroll
        for (int ar = 0; ar < 2; ++ar) {
          float hsel = gate == 0 ? hvf[ar][0] : gate == 1 ? hvf[ar][1]
                     : gate == 2 ? hvf[ar][2] : hvf[ar][3];
          float nsel = gate == 0 ? hn4[ar][0] : gate == 1 ? hn4[ar][1]
                     : gate == 2 ? hn4[ar][2] : hn4[ar][3];
          unsigned pk = (unsigned)f2b(hsel) | ((unsigned)f2b(nsel) << 16);
          const int row = rt2 * 32 + ar * 16 + lq * 4 + gate;
          __hip_atomic_store(hw32 + (size_t)row * 512 + ucol, pk,
                             __ATOMIC_RELAXED, __HIP_MEMORY_SCOPE_AGENT);
        }
      }

      // drain h-ring stores, then publish this block's flag (plain store, no RMW)
      asm volatile("s_waitcnt vmcnt(0)" ::: "memory");
      if (l == 0) {
        atomicAdd(&lds_arr, 1u);                 // LDS, monotonic
        if (w == 4) {
          long sp = 0;
          while (__hip_atomic_load(&lds_arr, __ATOMIC_RELAXED, __HIP_MEMORY_SCOPE_WORKGROUP)
                 < 4u * (unsigned)(t + 1)) {
            if (++sp > 50000000L) break;
            __builtin_amdgcn_s_sleep(1);
          }
          __hip_atomic_store(myflag, (unsigned)(t + 1), __ATOMIC_RELAXED, __HIP_MEMORY_SCOPE_AGENT);
        }
      }
    }
    __syncthreads();
  }

  // final output column: fout[511] (L1 x-waves)
  if (!is_h && fout) {
    const unsigned* sp32 = reinterpret_cast<const unsigned*>(
        hout + (size_t)(511 % hmod) * (64 * HID)) + (size_t)l * 512 + nb * 4 + (w & 3);
    unsigned pv = (hmod == 4)
        ? __hip_atomic_load(sp32, __ATOMIC_RELAXED, __HIP_MEMORY_SCOPE_AGENT)
        : *sp32;
    *reinterpret_cast<float2*>(fout + (size_t)l * (SEQ * HID) + (size_t)511 * HID
                               + nb * 8 + (w & 3) * 2) = make_float2(b2f_lo(pv), b2f_hi(pv));
  }
}

extern "C" void kernel_launch(void* const* d_in, const int* in_sizes, int n_in,
                              void* d_out, int out_size, void* d_ws, size_t ws_size,
                              hipStream_t stream) {
  const float* x   = (const float*)d_in[0];
  const float* Wx0 = (const float*)d_in[1];
  const float* Wh0 = (const float*)d_in[2];
  const float* b0  = (const float*)d_in[3];
  const float* Wx1 = (const float*)d_in[4];
  const float* Wh1 = (const float*)d_in[5];
  const float* b1  = (const float*)d_in[6];
  float* out = (float*)d_out;
  char* ws = (char*)d_ws;

  unsigned short* xb   = (unsigned short*)(ws);                  // 64 MB
  unsigned short* h1   = (unsigned short*)(ws + 67108864);       // 64 MB
  unsigned short* WxT0 = (unsigned short*)(ws + 134217728);      // 8 MB each
  unsigned short* WhT0 = (unsigned short*)(ws + 142606336);
  unsigned short* WxT1 = (unsigned short*)(ws + 150994944);
  unsigned short* WhT1 = (unsigned short*)(ws + 159383552);
  unsigned* bars       = (unsigned*)(ws + 167772160);            // 32 KB flags
  unsigned short* h2   = (unsigned short*)(ws + 167804928);
  int h2mod = (ws_size >= (size_t)167804928 + 67108864) ? 512 : 4;

  hipMemsetAsync(bars, 0, 32768, stream);
  k_castx<<<32768, 256, 0, stream>>>(x, xb);
  k_wtrans<<<4096, 256, 0, stream>>>(Wx0, WxT0);
  k_wtrans<<<4096, 256, 0, stream>>>(Wh0, WhT0);
  k_wtrans<<<4096, 256, 0, stream>>>(Wx1, WxT1);
  k_wtrans<<<4096, 256, 0, stream>>>(Wh1, WhT1);
  k_scan2<<<2 * NBLK, 512, 0, stream>>>(xb, WxT0, WhT0, b0, WxT1, WhT1, b1,
                                        h1, h2, h2mod, out, bars);
}